// Round 20
// baseline (141.397 us; speedup 1.0000x reference)
//
#include <hip/hip_runtime.h>

#define S_LEN 2048
#define NHEAD 16

using f32x4  = __attribute__((ext_vector_type(4))) float;
using f32x16 = __attribute__((ext_vector_type(16))) float;
using bf16x8 = __attribute__((ext_vector_type(8))) __bf16;

__device__ __forceinline__ unsigned short f2bf(float f) {
  union { float f; unsigned u; } v; v.f = f;
  unsigned r = v.u + 0x7FFFu + ((v.u >> 16) & 1u);
  return (unsigned short)(r >> 16);
}
__device__ __forceinline__ float bf2f(unsigned short h) {
  union { unsigned u; float f; } v; v.u = ((unsigned)h) << 16; return v.f;
}
__device__ __forceinline__ void unpack8(uint4 u, float x[8]) {
  x[0]=bf2f((unsigned short)(u.x&0xffff)); x[1]=bf2f((unsigned short)(u.x>>16));
  x[2]=bf2f((unsigned short)(u.y&0xffff)); x[3]=bf2f((unsigned short)(u.y>>16));
  x[4]=bf2f((unsigned short)(u.z&0xffff)); x[5]=bf2f((unsigned short)(u.z>>16));
  x[6]=bf2f((unsigned short)(u.w&0xffff)); x[7]=bf2f((unsigned short)(u.w>>16));
}
__device__ __forceinline__ uint4 pack8(const unsigned short o[8]) {
  uint4 u;
  u.x = (unsigned)o[0] | ((unsigned)o[1]<<16);
  u.y = (unsigned)o[2] | ((unsigned)o[3]<<16);
  u.z = (unsigned)o[4] | ((unsigned)o[5]<<16);
  u.w = (unsigned)o[6] | ((unsigned)o[7]<<16);
  return u;
}
__device__ __forceinline__ void gload16(const void* g, void* l) {
  __builtin_amdgcn_global_load_lds(
      (const __attribute__((address_space(1))) unsigned int*)g,
      (__attribute__((address_space(3))) unsigned int*)l, 16, 0, 0);
}
__device__ __forceinline__ float exp2_fast(float x) {
#if __has_builtin(__builtin_amdgcn_exp2f)
  return __builtin_amdgcn_exp2f(x);
#else
  return __expf(x * 0.6931471805599453f);
#endif
}
__device__ __forceinline__ void store_c(float* C, size_t off, float v) { C[off] = v; }
__device__ __forceinline__ void store_c(unsigned short* C, size_t off, float v) { C[off] = f2bf(v); }

// ---------------- fused prep: bf16 cvt + 2 weight transposes + RoPE trig table --------
__device__ __forceinline__ void transpose_body(const float* __restrict__ in,
                                               unsigned short* __restrict__ out,
                                               int R, int C, int r0, int c0,
                                               float (*T)[65], int tid) {
#pragma unroll
  for (int i = 0; i < 16; ++i) {
    int idx = tid + i * 256;
    int r = idx >> 6, c = idx & 63;
    T[r][c] = in[(size_t)(r0 + r) * C + c0 + c];
  }
  __syncthreads();
#pragma unroll
  for (int i = 0; i < 8; ++i) {
    int idx = tid + i * 256;
    int co = idx >> 5, rp = (idx & 31) * 2;
    unsigned v = (unsigned)f2bf(T[rp][co]) | ((unsigned)f2bf(T[rp + 1][co]) << 16);
    *(unsigned*)&out[(size_t)(c0 + co) * R + r0 + rp] = v;
  }
}

__global__ __launch_bounds__(256) void k_prep(const float* __restrict__ x,
                                              unsigned short* __restrict__ xb,
                                              const float* __restrict__ Wqkv,
                                              unsigned short* __restrict__ WqkvT,
                                              const float* __restrict__ Wout,
                                              unsigned short* __restrict__ WoutT,
                                              float2* __restrict__ tab) {
  __shared__ float T[64][65];
  int blk = blockIdx.x;
  int tid = threadIdx.x;
  if (blk < 2048) {
    int i = blk * 256 + tid;
    const float4* p = (const float4*)x + 2 * (size_t)i;
    float4 a = p[0], b = p[1];
    unsigned short o[8] = { f2bf(a.x), f2bf(a.y), f2bf(a.z), f2bf(a.w),
                            f2bf(b.x), f2bf(b.y), f2bf(b.z), f2bf(b.w) };
    ((uint4*)xb)[i] = pack8(o);
  } else if (blk < 2816) {
    int b2 = blk - 2048;
    transpose_body(Wqkv, WqkvT, 1024, 3072, (b2 & 15) * 64, (b2 >> 4) * 64, T, tid);
  } else if (blk < 3072) {
    int b3 = blk - 2816;
    transpose_body(Wout, WoutT, 1024, 1024, (b3 & 15) * 64, (b3 >> 4) * 64, T, tid);
  } else {
    int gt = (blk - 3072) * 256 + tid;
    int s = gt >> 2, quad = gt & 3;
#pragma unroll
    for (int j = 0; j < 8; ++j) {
      int pr = quad * 8 + j;
      float e2 = exp2_fast((float)pr * 0.41524101f);
      float freq = 1.0f / (e2 + 1.1920928955078125e-07f);
      float xx = (float)s * freq * 0.15915494309189535f;
      xx -= floorf(xx);
      float ang = xx * 6.283185307179586f;
      tab[(size_t)s * 32 + pr] = make_float2(__cosf(ang), __sinf(ang));
    }
  }
}

// ---------------- 128x128 bf16 GEMM, BK=64, dbuf, counted vmcnt + T2 swizzle ----------
template <typename OUT_T>
__global__ __launch_bounds__(256, 2) void k_gemm128(const unsigned short* __restrict__ A,
                                                    const unsigned short* __restrict__ Bt,
                                                    OUT_T* __restrict__ C,
                                                    int M, int N, int K) {
  __shared__ unsigned short As[2][128][64];
  __shared__ unsigned short Bs[2][128][64];
  const int tid = threadIdx.x;
  const int lane = tid & 63, w = tid >> 6;
  const int wm = w >> 1, wn = w & 1;
  const int li = lane & 15, g = lane >> 4;
  const int m0 = blockIdx.x * 128, n0 = blockIdx.y * 128;
  const int srow = w * 8 + (lane >> 3);
  const int scol = ((lane & 7) ^ ((lane >> 3) & 7)) * 8;

  f32x4 acc[4][4];
#pragma unroll
  for (int i = 0; i < 4; ++i)
#pragma unroll
    for (int j = 0; j < 4; ++j) acc[i][j] = (f32x4){0.f, 0.f, 0.f, 0.f};

  const int nt = K >> 6;

  auto stage_tile = [&](int kt) {
    int buf = kt & 1;
    const unsigned short* sa = A + (size_t)(m0 + srow) * K + kt * 64 + scol;
    const unsigned short* sb = Bt + (size_t)(n0 + srow) * K + kt * 64 + scol;
    char* da = (char*)&As[buf][srow][0];
    char* db = (char*)&Bs[buf][srow][0];
#pragma unroll
    for (int j = 0; j < 4; ++j) {
      gload16(sa + (size_t)(j * 32) * K, da + j * 32 * 128);
      gload16(sb + (size_t)(j * 32) * K, db + j * 32 * 128);
    }
  };

  stage_tile(0);

  for (int i = 0; i < nt; ++i) {
    if (i + 1 < nt) {
      stage_tile(i + 1);
      asm volatile("s_waitcnt vmcnt(8)" ::: "memory");
    } else {
      asm volatile("s_waitcnt vmcnt(0)" ::: "memory");
    }
    __builtin_amdgcn_s_barrier();
    asm volatile("" ::: "memory");
    const int buf = i & 1;
#pragma unroll
    for (int kk = 0; kk < 2; ++kk) {
      bf16x8 af[4], bfv[4];
      const int ps = ((kk << 2) | g) ^ (li & 7);
#pragma unroll
      for (int ii = 0; ii < 4; ++ii)
        af[ii] = *(const bf16x8*)&As[buf][wm * 64 + ii * 16 + li][ps * 8];
#pragma unroll
      for (int jj = 0; jj < 4; ++jj)
        bfv[jj] = *(const bf16x8*)&Bs[buf][wn * 64 + jj * 16 + li][ps * 8];
      __builtin_amdgcn_s_setprio(1);
#pragma unroll
      for (int ii = 0; ii < 4; ++ii)
#pragma unroll
        for (int jj = 0; jj < 4; ++jj)
          acc[ii][jj] = __builtin_amdgcn_mfma_f32_16x16x32_bf16(af[ii], bfv[jj],
                                                                acc[ii][jj], 0, 0, 0);
      __builtin_amdgcn_s_setprio(0);
    }
    asm volatile("" ::: "memory");
    __builtin_amdgcn_s_barrier();
    asm volatile("" ::: "memory");
  }

#pragma unroll
  for (int ii = 0; ii < 4; ++ii) {
    int row = m0 + wm * 64 + ii * 16 + g * 4;
#pragma unroll
    for (int jj = 0; jj < 4; ++jj) {
      int col = n0 + wn * 64 + jj * 16 + li;
#pragma unroll
      for (int r = 0; r < 4; ++r) store_c(C, (size_t)(row + r) * N + col, acc[ii][jj][r]);
    }
  }
}

// ---------------- rope + head split -> PRE-FRAGMENTED layouts (table-driven trig) -----
__global__ __launch_bounds__(256) void k_rope_split(const unsigned short* __restrict__ qkv,
                                                    const float2* __restrict__ tab,
                                                    unsigned short* __restrict__ Qf,
                                                    unsigned short* __restrict__ Kf,
                                                    unsigned short* __restrict__ Vf) {
  int blk = blockIdx.x;                 // b*512 + h*32 + st
  int st = blk & 31, h = (blk >> 5) & 15, b = blk >> 9;
  int s0 = st * 64;
  int tid = threadIdx.x;
  int sl = tid >> 2, quad = tid & 3;
  int s = s0 + sl;
  int bh = b * NHEAD + h;
  int l31 = s & 31;
  int qt = s >> 5;
  int cq = quad >> 1, hiq = quad & 1;

  float cs[8], sn[8];
  {
    const float2* tp = tab + (size_t)s * 32 + quad * 8;
#pragma unroll
    for (int j = 0; j < 8; ++j) { float2 t = tp[j]; cs[j] = t.x; sn[j] = t.y; }
  }
  const unsigned short* row = qkv + (size_t)(b * S_LEN + s) * 3072;
  const float QSC = 0.04508422f;   // (1/32) * log2(e)
  // Q -> Qf
  {
    float x1[8], x2[8];
    unpack8(*(const uint4*)&row[h * 64 + quad * 8], x1);
    unpack8(*(const uint4*)&row[h * 64 + 32 + quad * 8], x2);
    unsigned short o1[8], o2[8];
#pragma unroll
    for (int j = 0; j < 8; ++j) {
      o1[j] = f2bf((x1[j] * cs[j] - x2[j] * sn[j]) * QSC);
      o2[j] = f2bf((x2[j] * cs[j] + x1[j] * sn[j]) * QSC);
    }
    size_t base = ((size_t)bh * 64 + qt) * 4;
    int lane8 = (hiq * 32 + l31) * 8;
    *(uint4*)&Qf[(base + cq) * 512 + lane8] = pack8(o1);
    *(uint4*)&Qf[(base + 2 + cq) * 512 + lane8] = pack8(o2);
  }
  // K -> Kf (kperm baked)
  {
    float x1[8], x2[8];
    unpack8(*(const uint4*)&row[1024 + h * 64 + quad * 8], x1);
    unpack8(*(const uint4*)&row[1024 + h * 64 + 32 + quad * 8], x2);
    unsigned short o1[8], o2[8];
#pragma unroll
    for (int j = 0; j < 8; ++j) {
      o1[j] = f2bf(x1[j] * cs[j] - x2[j] * sn[j]);
      o2[j] = f2bf(x2[j] * cs[j] + x1[j] * sn[j]);
    }
    int lp = (l31 & 0x13) | ((l31 & 4) << 1) | ((l31 & 8) >> 1);
    size_t base = ((size_t)bh * 64 + qt) * 4;
    int lane8 = (hiq * 32 + lp) * 8;
    *(uint4*)&Kf[(base + cq) * 512 + lane8] = pack8(o1);
    *(uint4*)&Kf[(base + 2 + cq) * 512 + lane8] = pack8(o2);
  }
  // V: transpose 64x64 tile through LDS -> Vf fragments
  __shared__ unsigned short Vl[64 * 72];
#pragma unroll
  for (int i = 0; i < 2; ++i) {
    int c = tid + i * 256;
    int r = c >> 3, c8 = (c & 7) * 8;
    *(uint4*)&Vl[r * 72 + c8] =
        *(const uint4*)&qkv[(size_t)(b * S_LEN + s0 + r) * 3072 + 2048 + h * 64 + c8];
  }
  __syncthreads();
  int d = tid >> 2, sc4 = tid & 3;
  unsigned o[8];
#pragma unroll
  for (int jj = 0; jj < 8; ++jj) {
    int sidx = sc4 * 16 + jj * 2;
    o[jj] = (unsigned)Vl[sidx * 72 + d] | ((unsigned)Vl[(sidx + 1) * 72 + d] << 16);
  }
  {
    int t = st * 2 + (sc4 >> 1);
    int c = ((d >> 5) << 1) + (sc4 & 1);
    size_t base = (((size_t)bh * 64 + t) * 4 + c) * 512;
    *(uint4*)&Vf[base + (d & 31) * 8]        = make_uint4(o[0], o[1], o[2], o[3]);
    *(uint4*)&Vf[base + (32 + (d & 31)) * 8] = make_uint4(o[4], o[5], o[6], o[7]);
  }
}

// ---------------- causal flash attention, LDS-staged KV (k_attn6) ---------------------
// Block = (bh, group g): wave w owns qt = 4g+w; all waves walk KV tiles 0..4g+3 with
// double-buffered LDS staging via global_load_lds (in-flight data lives in LDS queue,
// NOT registers -> prefetch depth independent of regalloc; r14's VGPR-sink wall gone).
// Schedule = literal copy of k_gemm128's verified stage->vmcnt(N)->raw-barrier->compute
// ->raw-barrier loop (2 loads/wave/tile). Per-tile math = r14's verified single-tile
// path; epilogue = r3/4's verified per-wave path (no cross-wave merge needed).
__global__ __launch_bounds__(256) void k_attn6(const unsigned short* __restrict__ Qf,
                                               const unsigned short* __restrict__ Kf,
                                               const unsigned short* __restrict__ Vf,
                                               unsigned short* __restrict__ O) {
  __shared__ unsigned short KS[2][4][512];   // [buf][c][lane*8]  (4KB per buf)
  __shared__ unsigned short VS[2][4][512];
  __shared__ unsigned short OL[4][32 * 72];  // per-wave epilogue staging
  int bid = blockIdx.x;
  int i = (bid & 7) * 64 + (bid >> 3);       // XCD-bijective swizzle (512 % 8 == 0)
  int bh = i >> 4;
  int g = 15 - (i & 15);                     // big groups first
  int tid = threadIdx.x, w = tid >> 6, lane = tid & 63;
  int b = bh >> 4, h = bh & 15;
  int l31 = lane & 31, hi = lane >> 5;
  int qt = 4 * g + w;                        // this wave's q-tile
  int q0 = qt * 32;
  const int tmax = 4 * g + 3;                // block-uniform KV walk bound

  // Q fragments (per wave)
  const unsigned short* Qg = Qf + (((size_t)bh * 64 + qt) * 4) * 512 + lane * 8;
  bf16x8 qf[4];
#pragma unroll
  for (int c = 0; c < 4; ++c) qf[c] = *(const bf16x8*)(Qg + c * 512);

  float m_run = -1e30f, l_run = 0.f;
  f32x16 acc0, acc1;
#pragma unroll
  for (int r = 0; r < 16; ++r) { acc0[r] = 0.f; acc1[r] = 0.f; }

  // staging source: wave w fetches fragment c=w of each tile (1KB contiguous);
  // LDS dest wave-uniform base -> HW scatters lane*16 = exactly the fragment layout.
  const unsigned short* Kg = Kf + ((size_t)bh * 64) * 2048 + (size_t)w * 512 + lane * 8;
  const unsigned short* Vg = Vf + ((size_t)bh * 64) * 2048 + (size_t)w * 512 + lane * 8;
  auto stage = [&](int buf, int t) {
    gload16(Kg + (size_t)t * 2048, (char*)&KS[buf][w][0]);
    gload16(Vg + (size_t)t * 2048, (char*)&VS[buf][w][0]);
  };

  auto rescale_check = [&](float pmax) {
    if (__any(pmax > m_run + 8.0f)) {
      float pfull = fmaxf(pmax, __shfl_xor(pmax, 32));
      float mnew = fmaxf(m_run, pfull);
      float fac = exp2_fast(m_run - mnew);
      l_run *= fac;
#pragma unroll
      for (int r = 0; r < 16; ++r) { acc0[r] *= fac; acc1[r] *= fac; }
      m_run = mnew;
    }
  };
  auto cvt2 = [&](const f32x16& s, bf16x8& p0, bf16x8& p1) {
    unsigned w0, w1, w2, w3;
    asm("v_cvt_pk_bf16_f32 %0, %1, %2" : "=v"(w0) : "v"(s[0]), "v"(s[1]));
    asm("v_cvt_pk_bf16_f32 %0, %1, %2" : "=v"(w1) : "v"(s[2]), "v"(s[3]));
    asm("v_cvt_pk_bf16_f32 %0, %1, %2" : "=v"(w2) : "v"(s[4]), "v"(s[5]));
    asm("v_cvt_pk_bf16_f32 %0, %1, %2" : "=v"(w3) : "v"(s[6]), "v"(s[7]));
    union { uint4 uu; bf16x8 v; } cv;
    cv.uu = make_uint4(w0, w1, w2, w3);
    p0 = cv.v;
    asm("v_cvt_pk_bf16_f32 %0, %1, %2" : "=v"(w0) : "v"(s[8]), "v"(s[9]));
    asm("v_cvt_pk_bf16_f32 %0, %1, %2" : "=v"(w1) : "v"(s[10]), "v"(s[11]));
    asm("v_cvt_pk_bf16_f32 %0, %1, %2" : "=v"(w2) : "v"(s[12]), "v"(s[13]));
    asm("v_cvt_pk_bf16_f32 %0, %1, %2" : "=v"(w3) : "v"(s[14]), "v"(s[15]));
    cv.uu = make_uint4(w0, w1, w2, w3);
    p1 = cv.v;
  };

  stage(0, 0);   // 2 loads/wave in flight

  for (int t = 0; t <= tmax; ++t) {
    const int buf = t & 1;
    if (t < tmax) {
      stage(buf ^ 1, t + 1);                               // +2 -> 4 outstanding
      asm volatile("s_waitcnt vmcnt(2)" ::: "memory");     // tile t landed (own wave)
    } else {
      asm volatile("s_waitcnt vmcnt(0)" ::: "memory");     // drain final tile
    }
    asm volatile("" ::: "memory");
    __builtin_amdgcn_s_barrier();                          // tile t landed (all waves)
    asm volatile("" ::: "memory");
    if (t <= qt) {
      bf16x8 kf[4], vf[4];
#pragma unroll
      for (int c = 0; c < 4; ++c) kf[c] = *(const bf16x8*)&KS[buf][c][lane * 8];
#pragma unroll
      for (int c = 0; c < 4; ++c) vf[c] = *(const bf16x8*)&VS[buf][c][lane * 8];
      f32x16 s;
#pragma unroll
      for (int r = 0; r < 16; ++r) s[r] = 0.f;
      __builtin_amdgcn_s_setprio(1);
      s = __builtin_amdgcn_mfma_f32_32x32x16_bf16(kf[0], qf[0], s, 0, 0, 0);
      s = __builtin_amdgcn_mfma_f32_32x32x16_bf16(kf[1], qf[1], s, 0, 0, 0);
      s = __builtin_amdgcn_mfma_f32_32x32x16_bf16(kf[2], qf[2], s, 0, 0, 0);
      s = __builtin_amdgcn_mfma_f32_32x32x16_bf16(kf[3], qf[3], s, 0, 0, 0);
      __builtin_amdgcn_s_setprio(0);
      if (t == qt) {   // diagonal: mask kv > q (kv per permuted fragment layout)
#pragma unroll
        for (int r = 0; r < 16; ++r) {
          int kv = (r & 7) + 16 * (r >> 3) + 8 * hi;
          if (kv > l31) s[r] = -1e30f;
        }
      }
      float pmax;
      {
        float m0 = fmaxf(s[0], s[1]),   mm1 = fmaxf(s[2], s[3]);
        float m2 = fmaxf(s[4], s[5]),   m3 = fmaxf(s[6], s[7]);
        float m4 = fmaxf(s[8], s[9]),   m5 = fmaxf(s[10], s[11]);
        float m6 = fmaxf(s[12], s[13]), m7 = fmaxf(s[14], s[15]);
        m0 = fmaxf(m0, mm1); m2 = fmaxf(m2, m3); m4 = fmaxf(m4, m5); m6 = fmaxf(m6, m7);
        pmax = fmaxf(fmaxf(m0, m2), fmaxf(m4, m6));
      }
      rescale_check(pmax);
#pragma unroll
      for (int r = 0; r < 16; ++r) s[r] = exp2_fast(s[r] - m_run);
      {
        float s0 = (s[0] + s[1]) + (s[2] + s[3]);
        float s1 = (s[4] + s[5]) + (s[6] + s[7]);
        float s2 = (s[8] + s[9]) + (s[10] + s[11]);
        float s3 = (s[12] + s[13]) + (s[14] + s[15]);
        l_run += (s0 + s1) + (s2 + s3);
      }
      bf16x8 pf0, pf1;
      cvt2(s, pf0, pf1);
      __builtin_amdgcn_s_setprio(1);
      acc0 = __builtin_amdgcn_mfma_f32_32x32x16_bf16(vf[0], pf0, acc0, 0, 0, 0);
      acc0 = __builtin_amdgcn_mfma_f32_32x32x16_bf16(vf[1], pf1, acc0, 0, 0, 0);
      acc1 = __builtin_amdgcn_mfma_f32_32x32x16_bf16(vf[2], pf0, acc1, 0, 0, 0);
      acc1 = __builtin_amdgcn_mfma_f32_32x32x16_bf16(vf[3], pf1, acc1, 0, 0, 0);
      __builtin_amdgcn_s_setprio(0);
    }
    asm volatile("" ::: "memory");
    __builtin_amdgcn_s_barrier();                          // reads done before overwrite
    asm volatile("" ::: "memory");
  }

  // per-wave epilogue (r3/4-verified): no cross-wave merge needed
  float l_tot = l_run + __shfl_xor(l_run, 32);
  float inv = 1.0f / l_tot;
  unsigned short* ol = &OL[w][0];
#pragma unroll
  for (int dh = 0; dh < 2; ++dh) {
#pragma unroll
    for (int r = 0; r < 16; r += 2) {
      int dv = dh * 32 + (r & 3) + 8 * (r >> 2) + 4 * hi;
      float lo = (dh ? acc1[r] : acc0[r]) * inv;
      float hi_ = (dh ? acc1[r + 1] : acc0[r + 1]) * inv;
      unsigned uu;
      asm("v_cvt_pk_bf16_f32 %0, %1, %2" : "=v"(uu) : "v"(lo), "v"(hi_));
      *(unsigned*)&ol[l31 * 72 + dv] = uu;
    }
  }
  asm volatile("s_waitcnt lgkmcnt(0)" ::: "memory");
  {
    int q = lane >> 1, half = lane & 1;
    unsigned short* op = O + ((size_t)(b * S_LEN + q0 + q)) * 1024 + h * 64 + half * 32;
#pragma unroll
    for (int j = 0; j < 4; ++j)
      *(uint4*)(op + j * 8) = *(const uint4*)&ol[q * 72 + half * 32 + j * 8];
  }
}

extern "C" void kernel_launch(void* const* d_in, const int* in_sizes, int n_in,
                              void* d_out, int out_size, void* d_ws, size_t ws_size,
                              hipStream_t stream) {
  const float* x = (const float*)d_in[0];
  const float* Wqkv = (const float*)d_in[1];
  const float* Wout = (const float*)d_in[2];
  float* out = (float*)d_out;
  char* ws = (char*)d_ws;
  // layout (bytes): xb/O 0..8M | WqkvT 8..14M | WoutT 14..16M | qkv 16..40M |
  //                 Qf 40..48M | Kf 48..56M | Vf 56..64M
  // trig table (512KB) lives in d_out scratch (dead until final GEMM overwrites it).
  unsigned short* xb = (unsigned short*)(ws);
  unsigned short* WqkvT = (unsigned short*)(ws + ((size_t)8 << 20));
  unsigned short* WoutT = (unsigned short*)(ws + ((size_t)14 << 20));
  unsigned short* qkv = (unsigned short*)(ws + ((size_t)16 << 20));
  unsigned short* Qf = (unsigned short*)(ws + ((size_t)40 << 20));
  unsigned short* Kf = (unsigned short*)(ws + ((size_t)48 << 20));
  unsigned short* Vf = (unsigned short*)(ws + ((size_t)56 << 20));
  float2* trig = (float2*)d_out;

  k_prep<<<3104, 256, 0, stream>>>(x, xb, Wqkv, WqkvT, Wout, WoutT, trig);
  k_gemm128<unsigned short><<<dim3(32, 24), 256, 0, stream>>>(xb, WqkvT, qkv, 4096, 3072, 1024);
  k_rope_split<<<1024, 256, 0, stream>>>(qkv, trig, Qf, Kf, Vf);
  k_attn6<<<512, 256, 0, stream>>>(Qf, Kf, Vf, xb /* reuse as O [B][S][1024] */);
  k_gemm128<float><<<dim3(32, 8), 256, 0, stream>>>(xb, WoutT, out, 4096, 1024, 1024);
}

// Round 21
// 116.388 us; speedup vs baseline: 1.2149x; 1.2149x over previous
//
#include <hip/hip_runtime.h>

#define S_LEN 2048
#define NHEAD 16

using f32x4  = __attribute__((ext_vector_type(4))) float;
using f32x16 = __attribute__((ext_vector_type(16))) float;
using bf16x8 = __attribute__((ext_vector_type(8))) __bf16;

__device__ __forceinline__ unsigned short f2bf(float f) {
  union { float f; unsigned u; } v; v.f = f;
  unsigned r = v.u + 0x7FFFu + ((v.u >> 16) & 1u);
  return (unsigned short)(r >> 16);
}
__device__ __forceinline__ float bf2f(unsigned short h) {
  union { unsigned u; float f; } v; v.u = ((unsigned)h) << 16; return v.f;
}
__device__ __forceinline__ void unpack8(uint4 u, float x[8]) {
  x[0]=bf2f((unsigned short)(u.x&0xffff)); x[1]=bf2f((unsigned short)(u.x>>16));
  x[2]=bf2f((unsigned short)(u.y&0xffff)); x[3]=bf2f((unsigned short)(u.y>>16));
  x[4]=bf2f((unsigned short)(u.z&0xffff)); x[5]=bf2f((unsigned short)(u.z>>16));
  x[6]=bf2f((unsigned short)(u.w&0xffff)); x[7]=bf2f((unsigned short)(u.w>>16));
}
__device__ __forceinline__ uint4 pack8(const unsigned short o[8]) {
  uint4 u;
  u.x = (unsigned)o[0] | ((unsigned)o[1]<<16);
  u.y = (unsigned)o[2] | ((unsigned)o[3]<<16);
  u.z = (unsigned)o[4] | ((unsigned)o[5]<<16);
  u.w = (unsigned)o[6] | ((unsigned)o[7]<<16);
  return u;
}
__device__ __forceinline__ void gload16(const void* g, void* l) {
  __builtin_amdgcn_global_load_lds(
      (const __attribute__((address_space(1))) unsigned int*)g,
      (__attribute__((address_space(3))) unsigned int*)l, 16, 0, 0);
}
__device__ __forceinline__ float exp2_fast(float x) {
#if __has_builtin(__builtin_amdgcn_exp2f)
  return __builtin_amdgcn_exp2f(x);
#else
  return __expf(x * 0.6931471805599453f);
#endif
}
__device__ __forceinline__ void store_c(float* C, size_t off, float v) { C[off] = v; }
__device__ __forceinline__ void store_c(unsigned short* C, size_t off, float v) { C[off] = f2bf(v); }

// ---------------- fused prep: bf16 cvt + 2 weight transposes + RoPE trig table --------
// blocks [0,2048): x fp32 -> bf16 (8 elems/thread)
// blocks [2048,2816): Wqkv [1024][3072] -> WqkvT [3072][1024] bf16
// blocks [2816,3072): Wout [1024][1024] -> WoutT bf16
// blocks [3072,3104): trig table tab[s*32+pr] = (cos,sin); lives in d_out scratch
//                     (512KB of the 16MB output; final GEMM overwrites every element).
__device__ __forceinline__ void transpose_body(const float* __restrict__ in,
                                               unsigned short* __restrict__ out,
                                               int R, int C, int r0, int c0,
                                               float (*T)[65], int tid) {
#pragma unroll
  for (int i = 0; i < 16; ++i) {
    int idx = tid + i * 256;
    int r = idx >> 6, c = idx & 63;
    T[r][c] = in[(size_t)(r0 + r) * C + c0 + c];
  }
  __syncthreads();
#pragma unroll
  for (int i = 0; i < 8; ++i) {
    int idx = tid + i * 256;
    int co = idx >> 5, rp = (idx & 31) * 2;
    unsigned v = (unsigned)f2bf(T[rp][co]) | ((unsigned)f2bf(T[rp + 1][co]) << 16);
    *(unsigned*)&out[(size_t)(c0 + co) * R + r0 + rp] = v;
  }
}

__global__ __launch_bounds__(256) void k_prep(const float* __restrict__ x,
                                              unsigned short* __restrict__ xb,
                                              const float* __restrict__ Wqkv,
                                              unsigned short* __restrict__ WqkvT,
                                              const float* __restrict__ Wout,
                                              unsigned short* __restrict__ WoutT,
                                              float2* __restrict__ tab) {
  __shared__ float T[64][65];
  int blk = blockIdx.x;
  int tid = threadIdx.x;
  if (blk < 2048) {
    int i = blk * 256 + tid;                       // n8 = 524288 = 2048*256 exactly
    const float4* p = (const float4*)x + 2 * (size_t)i;
    float4 a = p[0], b = p[1];
    unsigned short o[8] = { f2bf(a.x), f2bf(a.y), f2bf(a.z), f2bf(a.w),
                            f2bf(b.x), f2bf(b.y), f2bf(b.z), f2bf(b.w) };
    ((uint4*)xb)[i] = pack8(o);
  } else if (blk < 2816) {
    int b2 = blk - 2048;
    transpose_body(Wqkv, WqkvT, 1024, 3072, (b2 & 15) * 64, (b2 >> 4) * 64, T, tid);
  } else if (blk < 3072) {
    int b3 = blk - 2816;
    transpose_body(Wout, WoutT, 1024, 1024, (b3 & 15) * 64, (b3 >> 4) * 64, T, tid);
  } else {
    int gt = (blk - 3072) * 256 + tid;             // [0, 8192)
    int s = gt >> 2, quad = gt & 3;
#pragma unroll
    for (int j = 0; j < 8; ++j) {
      int pr = quad * 8 + j;
      float e2 = exp2_fast((float)pr * 0.41524101f);
      float freq = 1.0f / (e2 + 1.1920928955078125e-07f);
      float xx = (float)s * freq * 0.15915494309189535f;   // revolutions
      xx -= floorf(xx);
      float ang = xx * 6.283185307179586f;                  // [0, 2pi)
      tab[(size_t)s * 32 + pr] = make_float2(__cosf(ang), __sinf(ang));
    }
  }
}

// ---------------- 128x128 bf16 GEMM, BK=64, dbuf, counted vmcnt + T2 swizzle ----------
// 2-D grid (m-fastest): default XCD assignment = m%8 -> A panels L2-resident per XCD.
template <typename OUT_T>
__global__ __launch_bounds__(256, 2) void k_gemm128(const unsigned short* __restrict__ A,
                                                    const unsigned short* __restrict__ Bt,
                                                    OUT_T* __restrict__ C,
                                                    int M, int N, int K) {
  __shared__ unsigned short As[2][128][64];
  __shared__ unsigned short Bs[2][128][64];
  const int tid = threadIdx.x;
  const int lane = tid & 63, w = tid >> 6;
  const int wm = w >> 1, wn = w & 1;
  const int li = lane & 15, g = lane >> 4;
  const int m0 = blockIdx.x * 128, n0 = blockIdx.y * 128;
  const int srow = w * 8 + (lane >> 3);                     // + j*32, j=0..3
  const int scol = ((lane & 7) ^ ((lane >> 3) & 7)) * 8;    // pre-swizzled source slot

  f32x4 acc[4][4];
#pragma unroll
  for (int i = 0; i < 4; ++i)
#pragma unroll
    for (int j = 0; j < 4; ++j) acc[i][j] = (f32x4){0.f, 0.f, 0.f, 0.f};

  const int nt = K >> 6;   // 64-wide K-tiles

  auto stage_tile = [&](int kt) {
    int buf = kt & 1;
    const unsigned short* sa = A + (size_t)(m0 + srow) * K + kt * 64 + scol;
    const unsigned short* sb = Bt + (size_t)(n0 + srow) * K + kt * 64 + scol;
    char* da = (char*)&As[buf][srow][0];
    char* db = (char*)&Bs[buf][srow][0];
#pragma unroll
    for (int j = 0; j < 4; ++j) {
      gload16(sa + (size_t)(j * 32) * K, da + j * 32 * 128);
      gload16(sb + (size_t)(j * 32) * K, db + j * 32 * 128);
    }
  };

  stage_tile(0);   // 8 loads/wave in flight

  for (int i = 0; i < nt; ++i) {
    if (i + 1 < nt) {
      stage_tile(i + 1);                                   // +8 -> 16 outstanding
      asm volatile("s_waitcnt vmcnt(8)" ::: "memory");     // tile i landed (own wave)
    } else {
      asm volatile("s_waitcnt vmcnt(0)" ::: "memory");     // drain final tile
    }
    __builtin_amdgcn_s_barrier();                          // tile i landed (all waves)
    asm volatile("" ::: "memory");
    const int buf = i & 1;
#pragma unroll
    for (int kk = 0; kk < 2; ++kk) {
      bf16x8 af[4], bfv[4];
      const int ps = ((kk << 2) | g) ^ (li & 7);           // swizzled physical slot
#pragma unroll
      for (int ii = 0; ii < 4; ++ii)
        af[ii] = *(const bf16x8*)&As[buf][wm * 64 + ii * 16 + li][ps * 8];
#pragma unroll
      for (int jj = 0; jj < 4; ++jj)
        bfv[jj] = *(const bf16x8*)&Bs[buf][wn * 64 + jj * 16 + li][ps * 8];
      __builtin_amdgcn_s_setprio(1);
#pragma unroll
      for (int ii = 0; ii < 4; ++ii)
#pragma unroll
        for (int jj = 0; jj < 4; ++jj)
          acc[ii][jj] = __builtin_amdgcn_mfma_f32_16x16x32_bf16(af[ii], bfv[jj],
                                                                acc[ii][jj], 0, 0, 0);
      __builtin_amdgcn_s_setprio(0);
    }
    asm volatile("" ::: "memory");
    __builtin_amdgcn_s_barrier();                          // reads done before overwrite
    asm volatile("" ::: "memory");
  }

#pragma unroll
  for (int ii = 0; ii < 4; ++ii) {
    int row = m0 + wm * 64 + ii * 16 + g * 4;
#pragma unroll
    for (int jj = 0; jj < 4; ++jj) {
      int col = n0 + wn * 64 + jj * 16 + li;
#pragma unroll
      for (int r = 0; r < 4; ++r) store_c(C, (size_t)(row + r) * N + col, acc[ii][jj][r]);
    }
  }
}

// ---------------- rope + head split -> PRE-FRAGMENTED layouts (table-driven trig) -----
__global__ __launch_bounds__(256) void k_rope_split(const unsigned short* __restrict__ qkv,
                                                    const float2* __restrict__ tab,
                                                    unsigned short* __restrict__ Qf,
                                                    unsigned short* __restrict__ Kf,
                                                    unsigned short* __restrict__ Vf) {
  int blk = blockIdx.x;                 // b*512 + h*32 + st
  int st = blk & 31, h = (blk >> 5) & 15, b = blk >> 9;
  int s0 = st * 64;
  int tid = threadIdx.x;
  int sl = tid >> 2, quad = tid & 3;
  int s = s0 + sl;
  int bh = b * NHEAD + h;
  int l31 = s & 31;
  int qt = s >> 5;
  int cq = quad >> 1, hiq = quad & 1;

  float cs[8], sn[8];
  {
    const float2* tp = tab + (size_t)s * 32 + quad * 8;
#pragma unroll
    for (int j = 0; j < 8; ++j) { float2 t = tp[j]; cs[j] = t.x; sn[j] = t.y; }
  }
  const unsigned short* row = qkv + (size_t)(b * S_LEN + s) * 3072;
  const float QSC = 0.04508422f;   // (1/32) * log2(e)
  // Q -> Qf
  {
    float x1[8], x2[8];
    unpack8(*(const uint4*)&row[h * 64 + quad * 8], x1);
    unpack8(*(const uint4*)&row[h * 64 + 32 + quad * 8], x2);
    unsigned short o1[8], o2[8];
#pragma unroll
    for (int j = 0; j < 8; ++j) {
      o1[j] = f2bf((x1[j] * cs[j] - x2[j] * sn[j]) * QSC);
      o2[j] = f2bf((x2[j] * cs[j] + x1[j] * sn[j]) * QSC);
    }
    size_t base = ((size_t)bh * 64 + qt) * 4;
    int lane8 = (hiq * 32 + l31) * 8;
    *(uint4*)&Qf[(base + cq) * 512 + lane8] = pack8(o1);
    *(uint4*)&Qf[(base + 2 + cq) * 512 + lane8] = pack8(o2);
  }
  // K -> Kf (kperm baked)
  {
    float x1[8], x2[8];
    unpack8(*(const uint4*)&row[1024 + h * 64 + quad * 8], x1);
    unpack8(*(const uint4*)&row[1024 + h * 64 + 32 + quad * 8], x2);
    unsigned short o1[8], o2[8];
#pragma unroll
    for (int j = 0; j < 8; ++j) {
      o1[j] = f2bf(x1[j] * cs[j] - x2[j] * sn[j]);
      o2[j] = f2bf(x2[j] * cs[j] + x1[j] * sn[j]);
    }
    int lp = (l31 & 0x13) | ((l31 & 4) << 1) | ((l31 & 8) >> 1);
    size_t base = ((size_t)bh * 64 + qt) * 4;
    int lane8 = (hiq * 32 + lp) * 8;
    *(uint4*)&Kf[(base + cq) * 512 + lane8] = pack8(o1);
    *(uint4*)&Kf[(base + 2 + cq) * 512 + lane8] = pack8(o2);
  }
  // V: transpose 64x64 tile through LDS -> Vf fragments
  __shared__ unsigned short Vl[64 * 72];
#pragma unroll
  for (int i = 0; i < 2; ++i) {
    int c = tid + i * 256;
    int r = c >> 3, c8 = (c & 7) * 8;
    *(uint4*)&Vl[r * 72 + c8] =
        *(const uint4*)&qkv[(size_t)(b * S_LEN + s0 + r) * 3072 + 2048 + h * 64 + c8];
  }
  __syncthreads();
  int d = tid >> 2, sc4 = tid & 3;
  unsigned o[8];
#pragma unroll
  for (int jj = 0; jj < 8; ++jj) {
    int sidx = sc4 * 16 + jj * 2;
    o[jj] = (unsigned)Vl[sidx * 72 + d] | ((unsigned)Vl[(sidx + 1) * 72 + d] << 16);
  }
  {
    int t = st * 2 + (sc4 >> 1);
    int c = ((d >> 5) << 1) + (sc4 & 1);
    size_t base = (((size_t)bh * 64 + t) * 4 + c) * 512;
    *(uint4*)&Vf[base + (d & 31) * 8]        = make_uint4(o[0], o[1], o[2], o[3]);
    *(uint4*)&Vf[base + (32 + (d & 31)) * 8] = make_uint4(o[4], o[5], o[6], o[7]);
  }
}

// ---------------- causal flash attention, 4-way split-KV, PAIRED KV tiles -------------
// Round-14 body byte-for-byte (best passing attn, 44.4us). launch_bounds(256,2) is
// POISONED on this body (r15+r16 NaN); LDS-staged variant regressed (r20: 67us).
// Default bounds; VGPR 120.
__global__ __launch_bounds__(256) void k_attn5(const unsigned short* __restrict__ Qf,
                                               const unsigned short* __restrict__ Kf,
                                               const unsigned short* __restrict__ Vf,
                                               unsigned short* __restrict__ O) {
  __shared__ float MBUF[3][2176];
  int bid = blockIdx.x;
  int i = (bid & 7) * 256 + (bid >> 3);   // XCD-bijective swizzle (2048 % 8 == 0)
  int bh = i >> 6;
  int qt = 63 - (i & 63);
  int tid = threadIdx.x, w = tid >> 6, lane = tid & 63;
  int b = bh >> 4, h = bh & 15;
  int l31 = lane & 31, hi = lane >> 5;

  int n = qt + 1;
  int t0 = (w * n) >> 2, t1 = ((w + 1) * n) >> 2;

  const unsigned short* Kg = Kf + ((size_t)bh * 64) * 4 * 512 + lane * 8;
  const unsigned short* Vg = Vf + ((size_t)bh * 64) * 4 * 512 + lane * 8;

  float m_run = -1e30f, l_run = 0.f;
  f32x16 acc0, acc1;
#pragma unroll
  for (int r = 0; r < 16; ++r) { acc0[r] = 0.f; acc1[r] = 0.f; }

  if (t0 < t1) {
    const unsigned short* Qg = Qf + (((size_t)bh * 64 + qt) * 4) * 512 + lane * 8;
    bf16x8 qf[4];
#pragma unroll
    for (int c = 0; c < 4; ++c) qf[c] = *(const bf16x8*)(Qg + c * 512);

    auto loadK = [&](bf16x8 (&kf)[4], int t) {
      const unsigned short* kp = Kg + (size_t)t * 2048;
#pragma unroll
      for (int c = 0; c < 4; ++c) kf[c] = *(const bf16x8*)(kp + c * 512);
    };
    auto loadV = [&](bf16x8 (&vf)[4], int t) {
      const unsigned short* vp = Vg + (size_t)t * 2048;
#pragma unroll
      for (int c = 0; c < 4; ++c) vf[c] = *(const bf16x8*)(vp + c * 512);
    };
    auto rescale_check = [&](float pmax) {
      if (__any(pmax > m_run + 8.0f)) {
        float pfull = fmaxf(pmax, __shfl_xor(pmax, 32));
        float mnew = fmaxf(m_run, pfull);
        float fac = exp2_fast(m_run - mnew);
        l_run *= fac;
#pragma unroll
        for (int r = 0; r < 16; ++r) { acc0[r] *= fac; acc1[r] *= fac; }
        m_run = mnew;
      }
    };
    auto cvt2 = [&](const f32x16& s, bf16x8& p0, bf16x8& p1) {
      unsigned w0, w1, w2, w3;
      asm("v_cvt_pk_bf16_f32 %0, %1, %2" : "=v"(w0) : "v"(s[0]), "v"(s[1]));
      asm("v_cvt_pk_bf16_f32 %0, %1, %2" : "=v"(w1) : "v"(s[2]), "v"(s[3]));
      asm("v_cvt_pk_bf16_f32 %0, %1, %2" : "=v"(w2) : "v"(s[4]), "v"(s[5]));
      asm("v_cvt_pk_bf16_f32 %0, %1, %2" : "=v"(w3) : "v"(s[6]), "v"(s[7]));
      union { uint4 uu; bf16x8 v; } cv;
      cv.uu = make_uint4(w0, w1, w2, w3);
      p0 = cv.v;
      asm("v_cvt_pk_bf16_f32 %0, %1, %2" : "=v"(w0) : "v"(s[8]), "v"(s[9]));
      asm("v_cvt_pk_bf16_f32 %0, %1, %2" : "=v"(w1) : "v"(s[10]), "v"(s[11]));
      asm("v_cvt_pk_bf16_f32 %0, %1, %2" : "=v"(w2) : "v"(s[12]), "v"(s[13]));
      asm("v_cvt_pk_bf16_f32 %0, %1, %2" : "=v"(w3) : "v"(s[14]), "v"(s[15]));
      cv.uu = make_uint4(w0, w1, w2, w3);
      p1 = cv.v;
    };

    bf16x8 kA[4], vA[4], kB[4], vB[4];
    loadK(kA, t0); loadV(vA, t0);
    if (t0 + 1 < t1) { loadK(kB, t0 + 1); loadV(vB, t0 + 1); }
    int t = t0;
    while (t + 1 < t1) {
      int tb = t + 1;
      f32x16 sa, sb;
#pragma unroll
      for (int r = 0; r < 16; ++r) { sa[r] = 0.f; sb[r] = 0.f; }
      __builtin_amdgcn_s_setprio(1);
      sa = __builtin_amdgcn_mfma_f32_32x32x16_bf16(kA[0], qf[0], sa, 0, 0, 0);
      sb = __builtin_amdgcn_mfma_f32_32x32x16_bf16(kB[0], qf[0], sb, 0, 0, 0);
      sa = __builtin_amdgcn_mfma_f32_32x32x16_bf16(kA[1], qf[1], sa, 0, 0, 0);
      sb = __builtin_amdgcn_mfma_f32_32x32x16_bf16(kB[1], qf[1], sb, 0, 0, 0);
      sa = __builtin_amdgcn_mfma_f32_32x32x16_bf16(kA[2], qf[2], sa, 0, 0, 0);
      sb = __builtin_amdgcn_mfma_f32_32x32x16_bf16(kB[2], qf[2], sb, 0, 0, 0);
      sa = __builtin_amdgcn_mfma_f32_32x32x16_bf16(kA[3], qf[3], sa, 0, 0, 0);
      sb = __builtin_amdgcn_mfma_f32_32x32x16_bf16(kB[3], qf[3], sb, 0, 0, 0);
      __builtin_amdgcn_s_setprio(0);
      if (t + 2 < t1) loadK(kA, t + 2);
      if (t + 3 < t1) loadK(kB, t + 3);
      if (tb == qt) {
#pragma unroll
        for (int r = 0; r < 16; ++r) {
          int kv = (r & 7) + 16 * (r >> 3) + 8 * hi;
          if (kv > l31) sb[r] = -1e30f;
        }
      }
      float pmax;
      {
        float m[8];
#pragma unroll
        for (int r = 0; r < 8; ++r)
          m[r] = fmaxf(fmaxf(sa[2 * r], sa[2 * r + 1]), fmaxf(sb[2 * r], sb[2 * r + 1]));
        m[0] = fmaxf(m[0], m[1]); m[2] = fmaxf(m[2], m[3]);
        m[4] = fmaxf(m[4], m[5]); m[6] = fmaxf(m[6], m[7]);
        pmax = fmaxf(fmaxf(m[0], m[2]), fmaxf(m[4], m[6]));
      }
      rescale_check(pmax);
#pragma unroll
      for (int r = 0; r < 16; ++r) {
        sa[r] = exp2_fast(sa[r] - m_run);
        sb[r] = exp2_fast(sb[r] - m_run);
      }
      {
        float t0_ = 0.f, t1_ = 0.f, t2_ = 0.f, t3_ = 0.f;
#pragma unroll
        for (int r = 0; r < 4; ++r) {
          t0_ += sa[r] + sb[r];
          t1_ += sa[4 + r] + sb[4 + r];
          t2_ += sa[8 + r] + sb[8 + r];
          t3_ += sa[12 + r] + sb[12 + r];
        }
        l_run += (t0_ + t1_) + (t2_ + t3_);
      }
      bf16x8 pa0, pa1, pb0, pb1;
      cvt2(sa, pa0, pa1);
      cvt2(sb, pb0, pb1);
      __builtin_amdgcn_s_setprio(1);
      acc0 = __builtin_amdgcn_mfma_f32_32x32x16_bf16(vA[0], pa0, acc0, 0, 0, 0);
      acc1 = __builtin_amdgcn_mfma_f32_32x32x16_bf16(vA[2], pa0, acc1, 0, 0, 0);
      acc0 = __builtin_amdgcn_mfma_f32_32x32x16_bf16(vA[1], pa1, acc0, 0, 0, 0);
      acc1 = __builtin_amdgcn_mfma_f32_32x32x16_bf16(vA[3], pa1, acc1, 0, 0, 0);
      acc0 = __builtin_amdgcn_mfma_f32_32x32x16_bf16(vB[0], pb0, acc0, 0, 0, 0);
      acc1 = __builtin_amdgcn_mfma_f32_32x32x16_bf16(vB[2], pb0, acc1, 0, 0, 0);
      acc0 = __builtin_amdgcn_mfma_f32_32x32x16_bf16(vB[1], pb1, acc0, 0, 0, 0);
      acc1 = __builtin_amdgcn_mfma_f32_32x32x16_bf16(vB[3], pb1, acc1, 0, 0, 0);
      __builtin_amdgcn_s_setprio(0);
      if (t + 2 < t1) loadV(vA, t + 2);
      if (t + 3 < t1) loadV(vB, t + 3);
      t += 2;
    }
    if (t < t1) {   // trailing single tile (always in buffer A)
      f32x16 s;
#pragma unroll
      for (int r = 0; r < 16; ++r) s[r] = 0.f;
      __builtin_amdgcn_s_setprio(1);
      s = __builtin_amdgcn_mfma_f32_32x32x16_bf16(kA[0], qf[0], s, 0, 0, 0);
      s = __builtin_amdgcn_mfma_f32_32x32x16_bf16(kA[1], qf[1], s, 0, 0, 0);
      s = __builtin_amdgcn_mfma_f32_32x32x16_bf16(kA[2], qf[2], s, 0, 0, 0);
      s = __builtin_amdgcn_mfma_f32_32x32x16_bf16(kA[3], qf[3], s, 0, 0, 0);
      __builtin_amdgcn_s_setprio(0);
      if (t == qt) {
#pragma unroll
        for (int r = 0; r < 16; ++r) {
          int kv = (r & 7) + 16 * (r >> 3) + 8 * hi;
          if (kv > l31) s[r] = -1e30f;
        }
      }
      float pmax;
      {
        float m0 = fmaxf(s[0], s[1]),   mm1 = fmaxf(s[2], s[3]);
        float m2 = fmaxf(s[4], s[5]),   m3 = fmaxf(s[6], s[7]);
        float m4 = fmaxf(s[8], s[9]),   m5 = fmaxf(s[10], s[11]);
        float m6 = fmaxf(s[12], s[13]), m7 = fmaxf(s[14], s[15]);
        m0 = fmaxf(m0, mm1); m2 = fmaxf(m2, m3); m4 = fmaxf(m4, m5); m6 = fmaxf(m6, m7);
        pmax = fmaxf(fmaxf(m0, m2), fmaxf(m4, m6));
      }
      rescale_check(pmax);
#pragma unroll
      for (int r = 0; r < 16; ++r) s[r] = exp2_fast(s[r] - m_run);
      {
        float s0 = (s[0] + s[1]) + (s[2] + s[3]);
        float s1 = (s[4] + s[5]) + (s[6] + s[7]);
        float s2 = (s[8] + s[9]) + (s[10] + s[11]);
        float s3 = (s[12] + s[13]) + (s[14] + s[15]);
        l_run += (s0 + s1) + (s2 + s3);
      }
      bf16x8 pf0, pf1;
      cvt2(s, pf0, pf1);
      __builtin_amdgcn_s_setprio(1);
      acc0 = __builtin_amdgcn_mfma_f32_32x32x16_bf16(vA[0], pf0, acc0, 0, 0, 0);
      acc0 = __builtin_amdgcn_mfma_f32_32x32x16_bf16(vA[1], pf1, acc0, 0, 0, 0);
      acc1 = __builtin_amdgcn_mfma_f32_32x32x16_bf16(vA[2], pf0, acc1, 0, 0, 0);
      acc1 = __builtin_amdgcn_mfma_f32_32x32x16_bf16(vA[3], pf1, acc1, 0, 0, 0);
      __builtin_amdgcn_s_setprio(0);
    }
  }

  // waves 1..3: stash partial (f32 acc + m + l) to slot w-1
  if (w != 0) {
    float* sb = &MBUF[w - 1][0];
#pragma unroll
    for (int r = 0; r < 16; ++r) {
      sb[r * 64 + lane] = acc0[r];
      sb[(16 + r) * 64 + lane] = acc1[r];
    }
    sb[2048 + lane] = m_run;
    sb[2112 + lane] = l_run;
  }
  __syncthreads();
  if (w == 0) {
    float m1 = MBUF[0][2048 + lane], m2 = MBUF[1][2048 + lane], m3 = MBUF[2][2048 + lane];
    float mF = fmaxf(fmaxf(m_run, m1), fmaxf(m2, m3));
    float f0 = exp2_fast(m_run - mF);
    float f1 = exp2_fast(m1 - mF);
    float f2 = exp2_fast(m2 - mF);
    float f3 = exp2_fast(m3 - mF);
    float lF = f0 * l_run + f1 * MBUF[0][2112 + lane] + f2 * MBUF[1][2112 + lane] +
               f3 * MBUF[2][2112 + lane];
    lF += __shfl_xor(lF, 32);
    float inv = 1.0f / lF;
    f32x16 o0, o1;
#pragma unroll
    for (int r = 0; r < 16; ++r) {
      o0[r] = (f0 * acc0[r] + f1 * MBUF[0][r * 64 + lane] + f2 * MBUF[1][r * 64 + lane] +
               f3 * MBUF[2][r * 64 + lane]) * inv;
      o1[r] = (f0 * acc1[r] + f1 * MBUF[0][(16 + r) * 64 + lane] +
               f2 * MBUF[1][(16 + r) * 64 + lane] + f3 * MBUF[2][(16 + r) * 64 + lane]) * inv;
    }
    unsigned short* ol = (unsigned short*)&MBUF[0][0];
#pragma unroll
    for (int dh = 0; dh < 2; ++dh) {
#pragma unroll
      for (int r = 0; r < 16; r += 2) {
        int dv = dh * 32 + (r & 3) + 8 * (r >> 2) + 4 * hi;
        float lo = dh ? o1[r] : o0[r];
        float hi_ = dh ? o1[r + 1] : o0[r + 1];
        unsigned uu;
        asm("v_cvt_pk_bf16_f32 %0, %1, %2" : "=v"(uu) : "v"(lo), "v"(hi_));
        *(unsigned*)&ol[l31 * 72 + dv] = uu;
      }
    }
    asm volatile("s_waitcnt lgkmcnt(0)" ::: "memory");
    int q0f = qt * 32;
    int q = lane >> 1, half = lane & 1;
    unsigned short* op = O + ((size_t)(b * S_LEN + q0f + q)) * 1024 + h * 64 + half * 32;
#pragma unroll
    for (int j = 0; j < 4; ++j)
      *(uint4*)(op + j * 8) = *(const uint4*)&ol[q * 72 + half * 32 + j * 8];
  }
}

extern "C" void kernel_launch(void* const* d_in, const int* in_sizes, int n_in,
                              void* d_out, int out_size, void* d_ws, size_t ws_size,
                              hipStream_t stream) {
  const float* x = (const float*)d_in[0];
  const float* Wqkv = (const float*)d_in[1];
  const float* Wout = (const float*)d_in[2];
  float* out = (float*)d_out;
  char* ws = (char*)d_ws;
  // layout (bytes): xb/O 0..8M | WqkvT 8..14M | WoutT 14..16M | qkv 16..40M |
  //                 Qf 40..48M | Kf 48..56M | Vf 56..64M
  // trig table (512KB) lives in d_out scratch (dead until final GEMM overwrites it).
  unsigned short* xb = (unsigned short*)(ws);
  unsigned short* WqkvT = (unsigned short*)(ws + ((size_t)8 << 20));
  unsigned short* WoutT = (unsigned short*)(ws + ((size_t)14 << 20));
  unsigned short* qkv = (unsigned short*)(ws + ((size_t)16 << 20));
  unsigned short* Qf = (unsigned short*)(ws + ((size_t)40 << 20));
  unsigned short* Kf = (unsigned short*)(ws + ((size_t)48 << 20));
  unsigned short* Vf = (unsigned short*)(ws + ((size_t)56 << 20));
  float2* trig = (float2*)d_out;

  k_prep<<<3104, 256, 0, stream>>>(x, xb, Wqkv, WqkvT, Wout, WoutT, trig);
  k_gemm128<unsigned short><<<dim3(32, 24), 256, 0, stream>>>(xb, WqkvT, qkv, 4096, 3072, 1024);
  k_rope_split<<<1024, 256, 0, stream>>>(qkv, trig, Qf, Kf, Vf);
  k_attn5<<<2048, 256, 0, stream>>>(Qf, Kf, Vf, xb /* reuse as O [B][S][1024] */);
  k_gemm128<float><<<dim3(32, 8), 256, 0, stream>>>(xb, WoutT, out, 4096, 1024, 1024);
}